// Round 2
// baseline (1841.124 us; speedup 1.0000x reference)
//
#include <hip/hip_runtime.h>
#include <hip/hip_bf16.h>
#include <stdint.h>

typedef __bf16 bf16_t;
typedef __bf16 bf16x8 __attribute__((ext_vector_type(8)));
typedef float  f32x4  __attribute__((ext_vector_type(4)));

#define HP 514   // padded spatial width (512 + 2)

__device__ __forceinline__ bf16_t f2bf(float f) { return (bf16_t)f; }

// ---------- L0: 1->64 1x1 conv + PReLU; fp32 NCHW -> padded NHWC bf16 ----------
__global__ void l0_kernel(const float* __restrict__ A, const float* __restrict__ w0,
                          const float* __restrict__ b0, const float* __restrict__ p0,
                          bf16_t* __restrict__ X0)
{
    int idx = blockIdx.x * 256 + threadIdx.x;
    if (idx >= HP * HP * 64) return;
    int c   = idx & 63;
    int pix = idx >> 6;
    int py = pix / HP, px = pix - py * HP;
    float v = 0.f;
    if (py >= 1 && py <= 512 && px >= 1 && px <= 512) {
        float a = A[(py - 1) * 512 + (px - 1)];
        v = fmaf(w0[c], a, b0[c]);
        v = v >= 0.f ? v : p0[0] * v;
    }
    X0[idx] = f2bf(v);
}

// ---------- zero full rows [r0, r0+n) of a strip buffer (width HP, C ch) ----------
__global__ void zero_rows_kernel(bf16_t* __restrict__ buf, int C, int r0, int n)
{
    int idx = blockIdx.x * 256 + threadIdx.x;
    int rowsz = HP * C;
    if (idx >= n * rowsz) return;
    int r = idx / rowsz, j = idx - r * rowsz;
    buf[(size_t)(r0 + r) * rowsz + j] = f2bf(0.f);
}

// ---------- zero cols 0 and 513 for rows [0, R) ----------
__global__ void zero_cols_kernel(bf16_t* __restrict__ buf, int C, int R)
{
    int idx = blockIdx.x * 256 + threadIdx.x;
    if (idx >= R * 2 * C) return;
    int r = idx / (2 * C);
    int t = idx - r * 2 * C;
    int col = (t < C) ? 0 : 513;
    int c = t % C;
    buf[((size_t)r * HP + col) * C + c] = f2bf(0.f);
}

// ---------- weight transform: OIHW fp32 -> [tap][cout][cin] bf16 ----------
__global__ void wtrans_kernel(const float* __restrict__ w, bf16_t* __restrict__ wt,
                              int COUT, int CIN)
{
    int idx = blockIdx.x * 256 + threadIdx.x;
    if (idx >= COUT * CIN * 9) return;
    int cin  = idx % CIN;
    int t    = idx / CIN;
    int cout = t % COUT;
    int tap  = t / COUT;
    wt[idx] = f2bf(w[(cout * CIN + cin) * 9 + tap]);
}

// ---------- 3x3 conv + bias + PReLU, implicit GEMM with bf16 MFMA ----------
// Block tile: 128 pixels (16y x 8x) x BN couts. 4 waves, wave tile 64 x BN/2.
// Generalized to row ranges: stores local output rows [0, n_rows) at out-buffer
// rows out_off+ly; reads in-buffer rows clamped to [0, in_alloc).
template<int CIN, int COUT, int BN>
__global__ __launch_bounds__(256, 2)
void conv3x3_kernel(const bf16_t* __restrict__ in, const bf16_t* __restrict__ wt,
                    const float* __restrict__ bias, const float* __restrict__ alpha,
                    bf16_t* __restrict__ out,
                    int n_rows, int in_off, int in_alloc, int out_off)
{
    constexpr int WN  = BN / 2;
    constexpr int NT  = WN / 16;
    constexpr int ASZ = 18 * 10 * 32;        // input slab elems per buffer
    constexpr int BSZ = BN * 32;             // weight tile elems per buffer
    constexpr int BCH = (BSZ * 2) / 4096;    // 4KB staging chunks (exact)
    __shared__ __align__(16) bf16_t As[2 * ASZ];
    __shared__ __align__(16) bf16_t Bs[2 * BSZ];

    const int tid  = threadIdx.x;
    const int lane = tid & 63;
    const int wave = tid >> 6;
    const int lm   = lane & 15;
    const int quad = lane >> 4;
    const int wave_m = wave >> 1;
    const int wave_n = wave & 1;

    const int x0    = blockIdx.x * 8;    // x of tile origin (padded-buffer col)
    const int y0    = blockIdx.y * 16;   // local output row base
    const int nbase = blockIdx.z * BN;

    // per-thread global source offsets for staging (channel-chunk added later)
    int a_g[3];
    #pragma unroll
    for (int it = 0; it < 3; ++it) {
        int e  = it * 2048 + tid * 8;
        int c  = e & 31;
        int px = (e >> 5) % 10;
        int r  = e / 320;
        int br = in_off + y0 + r;                       // input buffer row
        br = br < 0 ? 0 : (br >= in_alloc ? in_alloc - 1 : br);  // clamp (guarded out rows)
        a_g[it] = (br * HP + (x0 + px)) * CIN + c;
    }
    int b_g[BCH];
    #pragma unroll
    for (int it = 0; it < BCH; ++it) {
        int e = it * 2048 + tid * 8;
        int k = e & 31;
        int n = e >> 5;
        b_g[it] = (nbase + n) * CIN + k;
    }

    // per-thread LDS fragment read offsets (elements)
    int addrA0[4];
    #pragma unroll
    for (int mt = 0; mt < 4; ++mt) {
        int pyb = wave_m * 8 + mt * 2 + (lm >> 3);
        addrA0[mt] = (pyb * 10 + (lm & 7)) * 32 + quad * 8;
    }
    int addrB0[NT];
    #pragma unroll
    for (int nt = 0; nt < NT; ++nt)
        addrB0[nt] = (wave_n * WN + nt * 16 + lm) * 32 + quad * 8;

    auto stageA = [&](int cc, int ab) {
        #pragma unroll
        for (int it = 0; it < 3; ++it) {
            int e = it * 2048 + tid * 8;
            if (e < ASZ) {
                __builtin_amdgcn_global_load_lds(
                    (__attribute__((address_space(1))) void*)(in + a_g[it] + cc),
                    (__attribute__((address_space(3))) void*)(As + ab * ASZ + it * 2048 + wave * 512),
                    16, 0, 0);
            }
        }
    };
    auto stageB = [&](int cc, int tap, int bb) {
        const bf16_t* src = wt + tap * (COUT * CIN) + cc;
        #pragma unroll
        for (int it = 0; it < BCH; ++it) {
            __builtin_amdgcn_global_load_lds(
                (__attribute__((address_space(1))) void*)(src + b_g[it]),
                (__attribute__((address_space(3))) void*)(Bs + bb * BSZ + it * 2048 + wave * 512),
                16, 0, 0);
        }
    };

    f32x4 acc[4][NT] = {};

    stageA(0, 0);
    stageB(0, 0, 0);
    __syncthreads();

    int ab = 0, bb = 0;
    for (int cc = 0; cc < CIN; cc += 32) {
        #pragma unroll
        for (int tap = 0; tap < 9; ++tap) {
            // prefetch next tile(s) into the other buffers (drained by end barrier)
            if (tap < 8) {
                stageB(cc, tap + 1, bb ^ 1);
            } else if (cc + 32 < CIN) {
                stageA(cc + 32, ab ^ 1);
                stageB(cc + 32, 0, bb ^ 1);
            }
            const int dy = tap / 3, dx = tap % 3;
            const int shift = (dy * 10 + dx) * 32;
            bf16x8 a[4], b[NT];
            #pragma unroll
            for (int mt = 0; mt < 4; ++mt)
                a[mt] = *(const bf16x8*)(As + ab * ASZ + addrA0[mt] + shift);
            #pragma unroll
            for (int nt = 0; nt < NT; ++nt)
                b[nt] = *(const bf16x8*)(Bs + bb * BSZ + addrB0[nt]);
            #pragma unroll
            for (int mt = 0; mt < 4; ++mt) {
                #pragma unroll
                for (int nt = 0; nt < NT; ++nt)
                    acc[mt][nt] = __builtin_amdgcn_mfma_f32_16x16x32_bf16(
                        a[mt], b[nt], acc[mt][nt], 0, 0, 0);
            }
            bb ^= 1;
            __syncthreads();
        }
        ab ^= 1;
    }

    // epilogue: bias + PReLU, store bf16 into strip NHWC output (guarded rows)
    const float al = alpha[0];
    #pragma unroll
    for (int nt = 0; nt < NT; ++nt) {
        const int n = nbase + wave_n * WN + nt * 16 + lm;
        const float bv = bias[n];
        #pragma unroll
        for (int mt = 0; mt < 4; ++mt) {
            f32x4 v = acc[mt][nt];
            #pragma unroll
            for (int r = 0; r < 4; ++r) {
                int m  = wave_m * 64 + mt * 16 + quad * 4 + r;
                int py = m >> 3, px = m & 7;
                int ly = y0 + py;
                if (ly < n_rows) {
                    float f = v[r] + bv;
                    f = f >= 0.f ? f : al * f;
                    out[((size_t)(out_off + ly) * HP + (x0 + px + 1)) * COUT + n] = f2bf(f);
                }
            }
        }
    }
}

// ---------- L5 (64->1, k3) + bias + PReLU per strip, fp32 T out ----------
__device__ __forceinline__ float conv64_at(const bf16_t* __restrict__ X,
                                           const float* __restrict__ wsh,
                                           int y, int x, float bv)
{
    float acc = bv;
    #pragma unroll
    for (int dy = 0; dy < 3; ++dy) {
        #pragma unroll
        for (int dx = 0; dx < 3; ++dx) {
            const bf16x8* p = (const bf16x8*)(X + ((size_t)(y + dy) * HP + (x + dx)) * 64);
            const float* wf = wsh + (dy * 3 + dx) * 64;
            #pragma unroll
            for (int j = 0; j < 8; ++j) {
                bf16x8 v = p[j];
                #pragma unroll
                for (int k = 0; k < 8; ++k)
                    acc = fmaf((float)v[k], wf[j * 8 + k], acc);
            }
        }
    }
    return acc;
}

__global__ __launch_bounds__(256)
void l5_strip_kernel(const bf16_t* __restrict__ B4, const bf16_t* __restrict__ wt5,
                     const float* __restrict__ b5, const float* __restrict__ p5,
                     float* __restrict__ T, int abs_row0)
{
    __shared__ float wsh[9 * 64];
    for (int i = threadIdx.x; i < 576; i += 256) wsh[i] = (float)wt5[i];
    __syncthreads();
    int idx = blockIdx.x * 256 + threadIdx.x;   // S*512 threads exactly
    int ly = idx >> 9, x = idx & 511;
    float bv = b5[0], al = p5[0];
    // B4 row 0 <-> abs row abs_row0-1; output abs row abs_row0+ly reads rows ly..ly+2
    float t = conv64_at(B4, wsh, ly, x, bv);
    t = t >= 0.f ? t : al * t;
    T[(size_t)(abs_row0 + ly) * 512 + x] = t;
}

// ---------- final symmetrize: out = 0.5*(T + T^T) ----------
__global__ __launch_bounds__(256)
void sym_kernel(const float* __restrict__ T, float* __restrict__ out)
{
    int idx = blockIdx.x * 256 + threadIdx.x;   // 512*512 exactly
    int y = idx >> 9, x = idx & 511;
    out[idx] = 0.5f * (T[idx] + T[x * 512 + y]);
}

// ----------------------------------------------------------------------------
extern "C" void kernel_launch(void* const* d_in, const int* in_sizes, int n_in,
                              void* d_out, int out_size, void* d_ws, size_t ws_size,
                              hipStream_t stream)
{
    const float* A = (const float*)d_in[0];
    const float *w[6], *b[6], *p[6];
    for (int i = 0; i < 6; ++i) {
        w[i] = (const float*)d_in[1 + 3 * i];
        b[i] = (const float*)d_in[2 + 3 * i];
        p[i] = (const float*)d_in[3 + 3 * i];
    }

    // ---- choose strip height S: largest that fits ws_size ----
    auto footprint = [](long long S) -> size_t {
        auto al = [](size_t v) { return (v + 255) & ~(size_t)255; };
        size_t t = 0;
        t += al((size_t)HP * HP * 64 * 2);           // X0 (full)
        t += al((size_t)(S + 8) * HP * 256 * 2);     // B1 (also hosts B3)
        t += al((size_t)(S + 6) * HP * 512 * 2);     // B2
        t += al((size_t)(S + 2) * HP * 64 * 2);      // B4
        t += al((size_t)512 * 512 * 4);              // T
        t += al((size_t)9 * 256 * 64 * 2);
        t += al((size_t)9 * 512 * 256 * 2);
        t += al((size_t)9 * 256 * 512 * 2);
        t += al((size_t)9 * 64 * 256 * 2);
        t += al((size_t)9 * 64 * 2);
        return t;
    };
    const int cand[5] = {512, 128, 64, 32, 16};
    int S = 16;
    for (int i = 0; i < 5; ++i)
        if (footprint(cand[i]) <= ws_size) { S = cand[i]; break; }
    const int nStrips = 512 / S;

    // ---- carve workspace ----
    char* ws = (char*)d_ws;
    size_t off = 0;
    auto carve = [&](size_t bytes) -> void* {
        void* r = ws + off;
        off += (bytes + 255) & ~(size_t)255;
        return r;
    };
    bf16_t* X0  = (bf16_t*)carve((size_t)HP * HP * 64 * 2);
    bf16_t* B1  = (bf16_t*)carve((size_t)(S + 8) * HP * 256 * 2);
    bf16_t* B2  = (bf16_t*)carve((size_t)(S + 6) * HP * 512 * 2);
    bf16_t* B4  = (bf16_t*)carve((size_t)(S + 2) * HP * 64 * 2);
    float*  T   = (float*)carve((size_t)512 * 512 * 4);
    bf16_t* wt1 = (bf16_t*)carve((size_t)9 * 256 * 64 * 2);
    bf16_t* wt2 = (bf16_t*)carve((size_t)9 * 512 * 256 * 2);
    bf16_t* wt3 = (bf16_t*)carve((size_t)9 * 256 * 512 * 2);
    bf16_t* wt4 = (bf16_t*)carve((size_t)9 * 64 * 256 * 2);
    bf16_t* wt5 = (bf16_t*)carve((size_t)9 * 64 * 2);
    bf16_t* B3  = B1;   // alias: B1 dead after each strip's L2; same 256-ch layout

    auto cdiv = [](int a, int bq) { return (a + bq - 1) / bq; };
    auto zrows = [&](bf16_t* buf, int C, int r0, int n) {
        if (n > 0)
            zero_rows_kernel<<<cdiv(n * HP * C, 256), 256, 0, stream>>>(buf, C, r0, n);
    };

    // ---- setup: weights, X0, border columns ----
    wtrans_kernel<<<cdiv(9 * 256 * 64, 256), 256, 0, stream>>>(w[1], wt1, 256, 64);
    wtrans_kernel<<<cdiv(9 * 512 * 256, 256), 256, 0, stream>>>(w[2], wt2, 512, 256);
    wtrans_kernel<<<cdiv(9 * 256 * 512, 256), 256, 0, stream>>>(w[3], wt3, 256, 512);
    wtrans_kernel<<<cdiv(9 * 64 * 256, 256), 256, 0, stream>>>(w[4], wt4, 64, 256);
    wtrans_kernel<<<cdiv(9 * 1 * 64, 256), 256, 0, stream>>>(w[5], wt5, 1, 64);
    l0_kernel<<<cdiv(HP * HP * 64, 256), 256, 0, stream>>>(A, w[0], b[0], p[0], X0);
    zero_cols_kernel<<<cdiv((S + 8) * 2 * 256, 256), 256, 0, stream>>>(B1, 256, S + 8);
    zero_cols_kernel<<<cdiv((S + 6) * 2 * 512, 256), 256, 0, stream>>>(B2, 512, S + 6);
    zero_cols_kernel<<<cdiv((S + 2) * 2 * 64, 256), 256, 0, stream>>>(B4, 64, S + 2);

    // ---- strip pipeline ----
    for (int s = 0; s < nStrips; ++s) {
        const int base = S * s;
        int o0[5], nn[5], ooff[5], alloc[5];
        for (int k = 1; k <= 4; ++k) {
            int hk = 5 - k;                      // halos 4,3,2,1
            int a0 = base - hk, a1 = base + S + hk;
            int c0 = a0 < 0 ? 0 : a0, c1 = a1 > 512 ? 512 : a1;
            o0[k] = c0; nn[k] = c1 - c0; ooff[k] = c0 - a0; alloc[k] = S + 2 * hk;
        }
        // L1: X0 -> B1   (X0 row 0 <-> abs -1, alloc 514)
        {
            int in_off = o0[1];  // (o0-1) - (-1)
            dim3 g(64, cdiv(nn[1], 16), 2);
            conv3x3_kernel<64, 256, 128><<<g, 256, 0, stream>>>(
                X0, wt1, b[1], p[1], B1, nn[1], in_off, 514, ooff[1]);
            zrows(B1, 256, 0, ooff[1]);
            zrows(B1, 256, ooff[1] + nn[1], alloc[1] - ooff[1] - nn[1]);
        }
        // L2: B1 -> B2
        {
            int in_off = (o0[2] - 1) - (base - 4);
            dim3 g(64, cdiv(nn[2], 16), 4);
            conv3x3_kernel<256, 512, 128><<<g, 256, 0, stream>>>(
                B1, wt2, b[2], p[2], B2, nn[2], in_off, alloc[1], ooff[2]);
            zrows(B2, 512, 0, ooff[2]);
            zrows(B2, 512, ooff[2] + nn[2], alloc[2] - ooff[2] - nn[2]);
        }
        // L3: B2 -> B3 (= B1 memory; B1 fully consumed by L2 above)
        {
            int in_off = (o0[3] - 1) - (base - 3);
            dim3 g(64, cdiv(nn[3], 16), 2);
            conv3x3_kernel<512, 256, 128><<<g, 256, 0, stream>>>(
                B2, wt3, b[3], p[3], B3, nn[3], in_off, alloc[2], ooff[3]);
            zrows(B3, 256, 0, ooff[3]);
            zrows(B3, 256, ooff[3] + nn[3], alloc[3] - ooff[3] - nn[3]);
        }
        // L4: B3 -> B4
        {
            int in_off = (o0[4] - 1) - (base - 2);
            dim3 g(64, cdiv(nn[4], 16), 1);
            conv3x3_kernel<256, 64, 64><<<g, 256, 0, stream>>>(
                B3, wt4, b[4], p[4], B4, nn[4], in_off, alloc[3], ooff[4]);
            zrows(B4, 64, 0, ooff[4]);
            zrows(B4, 64, ooff[4] + nn[4], alloc[4] - ooff[4] - nn[4]);
        }
        // L5: B4 -> T rows [base, base+S)
        l5_strip_kernel<<<(S * 512) / 256, 256, 0, stream>>>(B4, wt5, b[5], p[5], T, base);
    }

    // final symmetrize
    sym_kernel<<<(512 * 512) / 256, 256, 0, stream>>>(T, (float*)d_out);
}